// Round 17
// baseline (7559.496 us; speedup 1.0000x reference)
//
#include <hip/hip_runtime.h>
#include <hip/hip_bf16.h>

#define B_  4096
#define D_  256
#define H3_ 3072
#define H_  2048
#define O_  128
#define T_  16

typedef unsigned short u16;
typedef unsigned char u8;

// Bit-exact model (VERIFIED r16, absmax=0): AOCL-BLIS sgemm, KC=512,
// single-accumulator micro-kernel:
//   K=256  -> [256]          (lat)
//   K=3072 -> [512 x 6]      (fusion)
//   K=2048 -> [512 x 4]      (spike GEMM, out GEMV)
// Per C element ONE f32 accumulator chained by fmaf over k ASCENDING within a
// panel; panels folded ascending (C = ((p0+p1)+p2)+...). Bias: one rn add.
// LIF: numpy ufunc order ((0.9*mem)+cur)-reset.
// r17 = SAME association, retiled for speed: 128x128 blocks, 8x8/thread
// (64 fmaf per 4 ds_read_b128 per k -> LDS-BW balanced vs VALU).

// ---------- pathway GEMMs: FUSED = relu(X @ W.T + b)  (K=256: single panel) ----------
__global__ __launch_bounds__(256) void lat_kernel(
    const float* __restrict__ dist, const float* __restrict__ azim, const float* __restrict__ elev,
    const float* __restrict__ Wd, const float* __restrict__ bd,
    const float* __restrict__ Wa, const float* __restrict__ ba,
    const float* __restrict__ We, const float* __restrict__ be,
    float* __restrict__ FUSED) {
  int nBase = blockIdx.x * 64;   // 0..3071
  int mBase = blockIdx.y * 64;   // 0..4095
  int p = nBase >> 10;
  const float* X  = (p == 0) ? dist : (p == 1) ? azim : elev;
  const float* W  = (p == 0) ? Wd   : (p == 1) ? Wa   : We;
  const float* bv = (p == 0) ? bd   : (p == 1) ? ba   : be;
  int nW = nBase - (p << 10);
  __shared__ float sAT[64][68];  // [k][m]
  __shared__ float sBT[64][68];  // [k][n]
  int tid = threadIdx.x;
  int tm = tid >> 4, tn = tid & 15;
  float acc[4][4] = {};
  for (int k0 = 0; k0 < D_; k0 += 64) {
#pragma unroll
    for (int pass = 0; pass < 4; ++pass) {
      int v = tid + pass * 256;
      int row = v & 63, c4 = (v >> 6) << 2;
      float4 a = *(const float4*)&X[(size_t)(mBase + row) * D_ + k0 + c4];
      sAT[c4 + 0][row] = a.x; sAT[c4 + 1][row] = a.y;
      sAT[c4 + 2][row] = a.z; sAT[c4 + 3][row] = a.w;
      float4 b = *(const float4*)&W[(size_t)(nW + row) * D_ + k0 + c4];
      sBT[c4 + 0][row] = b.x; sBT[c4 + 1][row] = b.y;
      sBT[c4 + 2][row] = b.z; sBT[c4 + 3][row] = b.w;
    }
    __syncthreads();
#pragma unroll 4
    for (int k = 0; k < 64; ++k) {
      float a4[4], b4[4];
      *(float4*)a4 = *(const float4*)&sAT[k][tm * 4];
      *(float4*)b4 = *(const float4*)&sBT[k][tn * 4];
#pragma unroll
      for (int i = 0; i < 4; ++i)
#pragma unroll
        for (int j = 0; j < 4; ++j)
          acc[i][j] = fmaf(a4[i], b4[j], acc[i][j]);
    }
    __syncthreads();
  }
#pragma unroll
  for (int i = 0; i < 4; ++i)
#pragma unroll
    for (int j = 0; j < 4; ++j) {
      float v = __fadd_rn(acc[i][j], bv[nW + tn * 4 + j]);
      FUSED[(size_t)(mBase + tm * 4 + i) * H3_ + nBase + tn * 4 + j] = fmaxf(v, 0.0f);
    }
}

// ---------- fusion GEMM: FC = FUSED @ Wf.T + bf; K=3072 = [512 x 6] ----------
// 128x128 tile, 8x8 per thread. Panel fold every 8 k-tiles (same association as r16).
__global__ __launch_bounds__(256, 2) void fusion_kernel(
    const float* __restrict__ A, const float* __restrict__ Wf,
    const float* __restrict__ bfv, float* __restrict__ FC) {
  __shared__ float sAT[64][132];  // [k][m], 16B-aligned rows
  __shared__ float sBT[64][132];  // [k][n]
  int tid = threadIdx.x;
  int tm = tid >> 4, tn = tid & 15;
  int mBase = blockIdx.y * 128, nBase = blockIdx.x * 128;
  int row = tid >> 1;            // 0..127
  int kh  = (tid & 1) << 5;      // 0 or 32
  float accP[8][8] = {};
  float accT[8][8] = {};
  for (int kb = 0; kb < 48; ++kb) {
    int k0 = kb << 6;
    const float* asrc = &A [(size_t)(mBase + row) * H3_ + k0 + kh];
    const float* bsrc = &Wf[(size_t)(nBase + row) * H3_ + k0 + kh];
#pragma unroll
    for (int u = 0; u < 8; ++u) {
      float4 av = *(const float4*)&asrc[u * 4];
      sAT[kh + u * 4 + 0][row] = av.x; sAT[kh + u * 4 + 1][row] = av.y;
      sAT[kh + u * 4 + 2][row] = av.z; sAT[kh + u * 4 + 3][row] = av.w;
      float4 bv = *(const float4*)&bsrc[u * 4];
      sBT[kh + u * 4 + 0][row] = bv.x; sBT[kh + u * 4 + 1][row] = bv.y;
      sBT[kh + u * 4 + 2][row] = bv.z; sBT[kh + u * 4 + 3][row] = bv.w;
    }
    __syncthreads();
#pragma unroll 2
    for (int k = 0; k < 64; ++k) {
      float a8[8], b8[8];
      *(float4*)&a8[0] = *(const float4*)&sAT[k][tm * 8];
      *(float4*)&a8[4] = *(const float4*)&sAT[k][tm * 8 + 4];
      *(float4*)&b8[0] = *(const float4*)&sBT[k][tn * 8];
      *(float4*)&b8[4] = *(const float4*)&sBT[k][tn * 8 + 4];
#pragma unroll
      for (int i = 0; i < 8; ++i)
#pragma unroll
        for (int j = 0; j < 8; ++j)
          accP[i][j] = fmaf(a8[i], b8[j], accP[i][j]);
    }
    __syncthreads();
    if ((kb & 7) == 7) {  // 512-panel boundary: 6 panels
#pragma unroll
      for (int i = 0; i < 8; ++i)
#pragma unroll
        for (int j = 0; j < 8; ++j) {
          accT[i][j] = __fadd_rn(accT[i][j], accP[i][j]);
          accP[i][j] = 0.0f;
        }
    }
  }
#pragma unroll
  for (int i = 0; i < 8; ++i)
#pragma unroll
    for (int j = 0; j < 8; ++j)
      FC[(size_t)(mBase + tm * 8 + i) * H_ + nBase + tn * 8 + j] =
          __fadd_rn(accT[i][j], bfv[nBase + tn * 8 + j]);
}

// ---------- fusion LIF: full recursion in-register, emit 16-bit spike mask ----------
__global__ __launch_bounds__(256) void spikegen16_kernel(
    const float* __restrict__ FC, u16* __restrict__ SPK) {
  int i = blockIdx.x * 256 + threadIdx.x;
  float fc = FC[i];
  float mem = 0.0f;
  unsigned bits = 0;
#pragma unroll
  for (int tt = 0; tt < T_; ++tt) {
    float reset = (mem > 1.0f) ? 1.0f : 0.0f;
    float nm = __fsub_rn(__fadd_rn(__fmul_rn(0.9f, mem), fc), reset);
    if (nm > 1.0f) bits |= (1u << tt);
    mem = nm;
  }
  SPK[i] = (u16)bits;
}

// ---------- spike GEMM (per t): icur = fspk_t @ Wi.T; K=2048 = [512 x 4]; fused LIF ----------
// 128x128 tile, 8x8 per thread. Panel fold every 8 k-tiles (same association as r16).
// fspk in {0,1}: fma(0,w,acc)==acc and +0.0f folds are bit-exact identities ->
// all-zero tiles skippable.
__global__ __launch_bounds__(256, 2) void isgemm_kernel(
    const u16* __restrict__ SPK, const float* __restrict__ Wi, const float* __restrict__ bi,
    float* __restrict__ IMEM, u8* __restrict__ CNT, int t) {
  __shared__ float sAT[64][132];  // [k][m]
  __shared__ float sBT[64][132];  // [k][n]
  __shared__ int sfl[4];
  int tid = threadIdx.x;
  int lane = tid & 63, wid = tid >> 6;
  int mBase = blockIdx.x * 128, nBase = blockIdx.y * 128;
  int tm = tid >> 4, tn = tid & 15;
  int row = tid >> 1;            // 0..127
  int kh  = (tid & 1) << 5;      // 0 or 32
  float accP[8][8] = {};
  float accT[8][8] = {};
  for (int kb = 0; kb < 32; ++kb) {
    int k0 = kb << 6;
    // stage A: spike bits (plane t) -> f32 transposed
    const u16* asrc = &SPK[(size_t)(mBase + row) * H_ + k0 + kh];
    unsigned anyb = 0;
#pragma unroll
    for (int u = 0; u < 4; ++u) {
      uint4 q = *(const uint4*)&asrc[u * 8];
      unsigned w4[4] = {q.x, q.y, q.z, q.w};
#pragma unroll
      for (int h = 0; h < 4; ++h) {
        unsigned blo = (w4[h] >> t) & 1u;
        unsigned bhi = (w4[h] >> (16 + t)) & 1u;
        anyb |= blo | bhi;
        sAT[kh + u * 8 + h * 2 + 0][row] = (float)blo;
        sAT[kh + u * 8 + h * 2 + 1][row] = (float)bhi;
      }
    }
    unsigned long long bb = __ballot(anyb != 0u);
    if (lane == 0) sfl[wid] = (bb != 0ull) ? 1 : 0;
    __syncthreads();
    int active = sfl[0] | sfl[1] | sfl[2] | sfl[3];  // block-uniform
    if (active) {
      const float* bsrc = &Wi[(size_t)(nBase + row) * H_ + k0 + kh];
#pragma unroll
      for (int u = 0; u < 8; ++u) {
        float4 bv = *(const float4*)&bsrc[u * 4];
        sBT[kh + u * 4 + 0][row] = bv.x; sBT[kh + u * 4 + 1][row] = bv.y;
        sBT[kh + u * 4 + 2][row] = bv.z; sBT[kh + u * 4 + 3][row] = bv.w;
      }
      __syncthreads();
#pragma unroll 2
      for (int k = 0; k < 64; ++k) {
        float a8[8], b8[8];
        *(float4*)&a8[0] = *(const float4*)&sAT[k][tm * 8];
        *(float4*)&a8[4] = *(const float4*)&sAT[k][tm * 8 + 4];
        *(float4*)&b8[0] = *(const float4*)&sBT[k][tn * 8];
        *(float4*)&b8[4] = *(const float4*)&sBT[k][tn * 8 + 4];
#pragma unroll
        for (int i = 0; i < 8; ++i)
#pragma unroll
          for (int j = 0; j < 8; ++j)
            accP[i][j] = fmaf(a8[i], b8[j], accP[i][j]);
      }
    }
    __syncthreads();
    if ((kb & 7) == 7) {  // 512-panel boundary: 4 panels
#pragma unroll
      for (int i = 0; i < 8; ++i)
#pragma unroll
        for (int j = 0; j < 8; ++j) {
          accT[i][j] = __fadd_rn(accT[i][j], accP[i][j]);
          accP[i][j] = 0.0f;
        }
    }
  }
  // fused integration LIF (exact f32 op order), CNT exact in u8
#pragma unroll
  for (int j = 0; j < 8; ++j) {
    int n = nBase + tn * 8 + j;
    float bvv = bi[n];
#pragma unroll
    for (int i = 0; i < 8; ++i) {
      int m = mBase + tm * 8 + i;
      size_t idx = (size_t)m * H_ + n;
      float cur = __fadd_rn(accT[i][j], bvv);
      float mem = (t == 0) ? 0.0f : IMEM[idx];
      float reset = (mem > 1.0f) ? 1.0f : 0.0f;
      float nm = __fsub_rn(__fadd_rn(__fmul_rn(0.9f, mem), cur), reset);
      IMEM[idx] = nm;
      u8 c0 = (t == 0) ? (u8)0 : CNT[idx];
      CNT[idx] = (u8)(c0 + ((nm > 1.0f) ? 1 : 0));
    }
  }
}

// ---------- output GEMV: out = (CNT/16) @ Wo.T + bo; K=2048 = [512 x 4] ----------
__global__ __launch_bounds__(256) void out_kernel(
    const u8* __restrict__ CNT, const float* __restrict__ Wo,
    const float* __restrict__ bo, float* __restrict__ out) {
  int i = blockIdx.x * 256 + threadIdx.x;
  int b = i >> 7, o = i & 127;
  const u8* pr = CNT + (size_t)b * H_;
  const float* wr = Wo + (size_t)o * H_;
  const int pend[4] = {512, 1024, 1536, 2048};
  float accT = 0.0f;
  int k = 0;
#pragma unroll
  for (int p = 0; p < 4; ++p) {
    float accP = 0.0f;
    for (; k < pend[p]; ++k)
      accP = fmaf((float)pr[k] * 0.0625f, wr[k], accP);  // pooled value exact
    accT = __fadd_rn(accT, accP);
  }
  out[i] = __fadd_rn(accT, bo[o]);
}

extern "C" void kernel_launch(void* const* d_in, const int* in_sizes, int n_in,
                              void* d_out, int out_size, void* d_ws, size_t ws_size,
                              hipStream_t stream) {
  const float* dist = (const float*)d_in[0];
  const float* azim = (const float*)d_in[1];
  const float* elev = (const float*)d_in[2];
  // d_in[3] spike_count: unused by the reference
  const float* Wd = (const float*)d_in[4];
  const float* bd = (const float*)d_in[5];
  const float* Wa = (const float*)d_in[6];
  const float* ba = (const float*)d_in[7];
  const float* We = (const float*)d_in[8];
  const float* be = (const float*)d_in[9];
  const float* Wf = (const float*)d_in[10];
  const float* bf = (const float*)d_in[11];
  const float* Wi = (const float*)d_in[12];
  const float* bi = (const float*)d_in[13];
  const float* Wo = (const float*)d_in[14];
  const float* bo = (const float*)d_in[15];

  char* ws = (char*)d_ws;
  const size_t MB = 1u << 20;
  // Footprint 136 MB, no aliasing.
  float* FUSED = (float*)(ws);             // [0,48)   4096x3072 f32
  float* FC    = (float*)(ws + 48 * MB);   // [48,80)  4096x2048 f32
  u16*   SPK   = (u16*)(ws + 80 * MB);     // [80,96)  4096x2048 u16 bitmask
  float* IMEM  = (float*)(ws + 96 * MB);   // [96,128) 4096x2048 f32
  u8*    CNT   = (u8*)(ws + 128 * MB);     // [128,136) 4096x2048 u8

  lat_kernel<<<dim3(48, 64), 256, 0, stream>>>(dist, azim, elev, Wd, bd, Wa, ba, We, be, FUSED);
  fusion_kernel<<<dim3(16, 32), 256, 0, stream>>>(FUSED, Wf, bf, FC);
  spikegen16_kernel<<<(B_ * H_) / 256, 256, 0, stream>>>(FC, SPK);
  for (int t = 0; t < T_; ++t)
    isgemm_kernel<<<dim3(32, 16), 256, 0, stream>>>(SPK, Wi, bi, IMEM, CNT, t);
  out_kernel<<<(B_ * O_) / 256, 256, 0, stream>>>(CNT, Wo, bo, (float*)d_out);
}

// Round 18
// 7096.437 us; speedup vs baseline: 1.0653x; 1.0653x over previous
//
#include <hip/hip_runtime.h>
#include <hip/hip_bf16.h>

#define B_  4096
#define D_  256
#define H3_ 3072
#define H_  2048
#define O_  128
#define T_  16

typedef unsigned short u16;
typedef unsigned char u8;

// Bit-exact model (VERIFIED r16, absmax=0): AOCL-BLIS sgemm, KC=512,
// single-accumulator micro-kernel:
//   K=256  -> [256]          (lat)
//   K=3072 -> [512 x 6]      (fusion)
//   K=2048 -> [512 x 4]      (spike GEMM, out GEMV)
// Per C element ONE f32 accumulator chained by fmaf over k ASCENDING within a
// panel; panels folded ascending (C = ((p0+p1)+p2)+...). Bias: one rn add.
// LIF: numpy ufunc order ((0.9*mem)+cur)-reset.
// r18 = r17 retile with BANK-CONFLICT-FREE addressing: 8x8/thread split as
// (4+4)x(4+4) at offsets {tm*4, 64+tm*4} x {tn*4, 64+tn*4}. 16 lanes read
// stride-16B -> 2 lanes/bank (free, m136). Association per element unchanged.

// ---------- pathway GEMMs: FUSED = relu(X @ W.T + b)  (K=256: single panel) ----------
__global__ __launch_bounds__(256) void lat_kernel(
    const float* __restrict__ dist, const float* __restrict__ azim, const float* __restrict__ elev,
    const float* __restrict__ Wd, const float* __restrict__ bd,
    const float* __restrict__ Wa, const float* __restrict__ ba,
    const float* __restrict__ We, const float* __restrict__ be,
    float* __restrict__ FUSED) {
  int nBase = blockIdx.x * 64;   // 0..3071
  int mBase = blockIdx.y * 64;   // 0..4095
  int p = nBase >> 10;
  const float* X  = (p == 0) ? dist : (p == 1) ? azim : elev;
  const float* W  = (p == 0) ? Wd   : (p == 1) ? Wa   : We;
  const float* bv = (p == 0) ? bd   : (p == 1) ? ba   : be;
  int nW = nBase - (p << 10);
  __shared__ float sAT[64][68];  // [k][m]
  __shared__ float sBT[64][68];  // [k][n]
  int tid = threadIdx.x;
  int tm = tid >> 4, tn = tid & 15;
  float acc[4][4] = {};
  for (int k0 = 0; k0 < D_; k0 += 64) {
#pragma unroll
    for (int pass = 0; pass < 4; ++pass) {
      int v = tid + pass * 256;
      int row = v & 63, c4 = (v >> 6) << 2;
      float4 a = *(const float4*)&X[(size_t)(mBase + row) * D_ + k0 + c4];
      sAT[c4 + 0][row] = a.x; sAT[c4 + 1][row] = a.y;
      sAT[c4 + 2][row] = a.z; sAT[c4 + 3][row] = a.w;
      float4 b = *(const float4*)&W[(size_t)(nW + row) * D_ + k0 + c4];
      sBT[c4 + 0][row] = b.x; sBT[c4 + 1][row] = b.y;
      sBT[c4 + 2][row] = b.z; sBT[c4 + 3][row] = b.w;
    }
    __syncthreads();
#pragma unroll 4
    for (int k = 0; k < 64; ++k) {
      float a4[4], b4[4];
      *(float4*)a4 = *(const float4*)&sAT[k][tm * 4];
      *(float4*)b4 = *(const float4*)&sBT[k][tn * 4];
#pragma unroll
      for (int i = 0; i < 4; ++i)
#pragma unroll
        for (int j = 0; j < 4; ++j)
          acc[i][j] = fmaf(a4[i], b4[j], acc[i][j]);
    }
    __syncthreads();
  }
#pragma unroll
  for (int i = 0; i < 4; ++i)
#pragma unroll
    for (int j = 0; j < 4; ++j) {
      float v = __fadd_rn(acc[i][j], bv[nW + tn * 4 + j]);
      FUSED[(size_t)(mBase + tm * 4 + i) * H3_ + nBase + tn * 4 + j] = fmaxf(v, 0.0f);
    }
}

// ---------- fusion GEMM: FC = FUSED @ Wf.T + bf; K=3072 = [512 x 6] ----------
// 128x128 tile, 8x8/thread as (4+4)x(4+4). Panel fold every 8 k-tiles.
__global__ __launch_bounds__(256, 2) void fusion_kernel(
    const float* __restrict__ A, const float* __restrict__ Wf,
    const float* __restrict__ bfv, float* __restrict__ FC) {
  __shared__ float sAT[64][132];  // [k][m]
  __shared__ float sBT[64][132];  // [k][n]
  int tid = threadIdx.x;
  int tm = tid >> 4, tn = tid & 15;
  int mBase = blockIdx.y * 128, nBase = blockIdx.x * 128;
  int row = tid >> 1;            // 0..127
  int kh  = (tid & 1) << 5;      // 0 or 32
  float accP[8][8] = {};
  float accT[8][8] = {};
  for (int kb = 0; kb < 48; ++kb) {
    int k0 = kb << 6;
    const float* asrc = &A [(size_t)(mBase + row) * H3_ + k0 + kh];
    const float* bsrc = &Wf[(size_t)(nBase + row) * H3_ + k0 + kh];
#pragma unroll
    for (int u = 0; u < 8; ++u) {
      float4 av = *(const float4*)&asrc[u * 4];
      sAT[kh + u * 4 + 0][row] = av.x; sAT[kh + u * 4 + 1][row] = av.y;
      sAT[kh + u * 4 + 2][row] = av.z; sAT[kh + u * 4 + 3][row] = av.w;
      float4 bv = *(const float4*)&bsrc[u * 4];
      sBT[kh + u * 4 + 0][row] = bv.x; sBT[kh + u * 4 + 1][row] = bv.y;
      sBT[kh + u * 4 + 2][row] = bv.z; sBT[kh + u * 4 + 3][row] = bv.w;
    }
    __syncthreads();
#pragma unroll 2
    for (int k = 0; k < 64; ++k) {
      float a8[8], b8[8];
      *(float4*)&a8[0] = *(const float4*)&sAT[k][tm * 4];        // rows tm*4..+3
      *(float4*)&a8[4] = *(const float4*)&sAT[k][64 + tm * 4];   // rows 64+tm*4..+3
      *(float4*)&b8[0] = *(const float4*)&sBT[k][tn * 4];        // cols tn*4..+3
      *(float4*)&b8[4] = *(const float4*)&sBT[k][64 + tn * 4];   // cols 64+tn*4..+3
#pragma unroll
      for (int i = 0; i < 8; ++i)
#pragma unroll
        for (int j = 0; j < 8; ++j)
          accP[i][j] = fmaf(a8[i], b8[j], accP[i][j]);
    }
    __syncthreads();
    if ((kb & 7) == 7) {  // 512-panel boundary: 6 panels
#pragma unroll
      for (int i = 0; i < 8; ++i)
#pragma unroll
        for (int j = 0; j < 8; ++j) {
          accT[i][j] = __fadd_rn(accT[i][j], accP[i][j]);
          accP[i][j] = 0.0f;
        }
    }
  }
#pragma unroll
  for (int i = 0; i < 8; ++i) {
    int m = mBase + ((i < 4) ? (tm * 4 + i) : (64 + tm * 4 + i - 4));
#pragma unroll
    for (int j = 0; j < 8; ++j) {
      int n = nBase + ((j < 4) ? (tn * 4 + j) : (64 + tn * 4 + j - 4));
      FC[(size_t)m * H_ + n] = __fadd_rn(accT[i][j], bfv[n]);
    }
  }
}

// ---------- fusion LIF: full recursion in-register, emit 16-bit spike mask ----------
__global__ __launch_bounds__(256) void spikegen16_kernel(
    const float* __restrict__ FC, u16* __restrict__ SPK) {
  int i = blockIdx.x * 256 + threadIdx.x;
  float fc = FC[i];
  float mem = 0.0f;
  unsigned bits = 0;
#pragma unroll
  for (int tt = 0; tt < T_; ++tt) {
    float reset = (mem > 1.0f) ? 1.0f : 0.0f;
    float nm = __fsub_rn(__fadd_rn(__fmul_rn(0.9f, mem), fc), reset);
    if (nm > 1.0f) bits |= (1u << tt);
    mem = nm;
  }
  SPK[i] = (u16)bits;
}

// ---------- spike GEMM (per t): icur = fspk_t @ Wi.T; K=2048 = [512 x 4]; fused LIF ----------
// 128x128 tile, 8x8/thread as (4+4)x(4+4). Panel fold every 8 k-tiles.
// fspk in {0,1}: fma(0,w,acc)==acc and +0.0f folds are bit-exact identities ->
// all-zero tiles skippable.
__global__ __launch_bounds__(256, 2) void isgemm_kernel(
    const u16* __restrict__ SPK, const float* __restrict__ Wi, const float* __restrict__ bi,
    float* __restrict__ IMEM, u8* __restrict__ CNT, int t) {
  __shared__ float sAT[64][132];  // [k][m]
  __shared__ float sBT[64][132];  // [k][n]
  __shared__ int sfl[4];
  int tid = threadIdx.x;
  int lane = tid & 63, wid = tid >> 6;
  int mBase = blockIdx.x * 128, nBase = blockIdx.y * 128;
  int tm = tid >> 4, tn = tid & 15;
  int row = tid >> 1;            // 0..127
  int kh  = (tid & 1) << 5;      // 0 or 32
  float accP[8][8] = {};
  float accT[8][8] = {};
  for (int kb = 0; kb < 32; ++kb) {
    int k0 = kb << 6;
    // stage A: spike bits (plane t) -> f32 transposed
    const u16* asrc = &SPK[(size_t)(mBase + row) * H_ + k0 + kh];
    unsigned anyb = 0;
#pragma unroll
    for (int u = 0; u < 4; ++u) {
      uint4 q = *(const uint4*)&asrc[u * 8];
      unsigned w4[4] = {q.x, q.y, q.z, q.w};
#pragma unroll
      for (int h = 0; h < 4; ++h) {
        unsigned blo = (w4[h] >> t) & 1u;
        unsigned bhi = (w4[h] >> (16 + t)) & 1u;
        anyb |= blo | bhi;
        sAT[kh + u * 8 + h * 2 + 0][row] = (float)blo;
        sAT[kh + u * 8 + h * 2 + 1][row] = (float)bhi;
      }
    }
    unsigned long long bb = __ballot(anyb != 0u);
    if (lane == 0) sfl[wid] = (bb != 0ull) ? 1 : 0;
    __syncthreads();
    int active = sfl[0] | sfl[1] | sfl[2] | sfl[3];  // block-uniform
    if (active) {
      const float* bsrc = &Wi[(size_t)(nBase + row) * H_ + k0 + kh];
#pragma unroll
      for (int u = 0; u < 8; ++u) {
        float4 bv = *(const float4*)&bsrc[u * 4];
        sBT[kh + u * 4 + 0][row] = bv.x; sBT[kh + u * 4 + 1][row] = bv.y;
        sBT[kh + u * 4 + 2][row] = bv.z; sBT[kh + u * 4 + 3][row] = bv.w;
      }
      __syncthreads();
#pragma unroll 2
      for (int k = 0; k < 64; ++k) {
        float a8[8], b8[8];
        *(float4*)&a8[0] = *(const float4*)&sAT[k][tm * 4];
        *(float4*)&a8[4] = *(const float4*)&sAT[k][64 + tm * 4];
        *(float4*)&b8[0] = *(const float4*)&sBT[k][tn * 4];
        *(float4*)&b8[4] = *(const float4*)&sBT[k][64 + tn * 4];
#pragma unroll
        for (int i = 0; i < 8; ++i)
#pragma unroll
          for (int j = 0; j < 8; ++j)
            accP[i][j] = fmaf(a8[i], b8[j], accP[i][j]);
      }
    }
    __syncthreads();
    if ((kb & 7) == 7) {  // 512-panel boundary: 4 panels
#pragma unroll
      for (int i = 0; i < 8; ++i)
#pragma unroll
        for (int j = 0; j < 8; ++j) {
          accT[i][j] = __fadd_rn(accT[i][j], accP[i][j]);
          accP[i][j] = 0.0f;
        }
    }
  }
  // fused integration LIF (exact f32 op order), CNT exact in u8
#pragma unroll
  for (int j = 0; j < 8; ++j) {
    int n = nBase + ((j < 4) ? (tn * 4 + j) : (64 + tn * 4 + j - 4));
    float bvv = bi[n];
#pragma unroll
    for (int i = 0; i < 8; ++i) {
      int m = mBase + ((i < 4) ? (tm * 4 + i) : (64 + tm * 4 + i - 4));
      size_t idx = (size_t)m * H_ + n;
      float cur = __fadd_rn(accT[i][j], bvv);
      float mem = (t == 0) ? 0.0f : IMEM[idx];
      float reset = (mem > 1.0f) ? 1.0f : 0.0f;
      float nm = __fsub_rn(__fadd_rn(__fmul_rn(0.9f, mem), cur), reset);
      IMEM[idx] = nm;
      u8 c0 = (t == 0) ? (u8)0 : CNT[idx];
      CNT[idx] = (u8)(c0 + ((nm > 1.0f) ? 1 : 0));
    }
  }
}

// ---------- output GEMV: out = (CNT/16) @ Wo.T + bo; K=2048 = [512 x 4] ----------
__global__ __launch_bounds__(256) void out_kernel(
    const u8* __restrict__ CNT, const float* __restrict__ Wo,
    const float* __restrict__ bo, float* __restrict__ out) {
  int i = blockIdx.x * 256 + threadIdx.x;
  int b = i >> 7, o = i & 127;
  const u8* pr = CNT + (size_t)b * H_;
  const float* wr = Wo + (size_t)o * H_;
  const int pend[4] = {512, 1024, 1536, 2048};
  float accT = 0.0f;
  int k = 0;
#pragma unroll
  for (int p = 0; p < 4; ++p) {
    float accP = 0.0f;
    for (; k < pend[p]; ++k)
      accP = fmaf((float)pr[k] * 0.0625f, wr[k], accP);  // pooled value exact
    accT = __fadd_rn(accT, accP);
  }
  out[i] = __fadd_rn(accT, bo[o]);
}

extern "C" void kernel_launch(void* const* d_in, const int* in_sizes, int n_in,
                              void* d_out, int out_size, void* d_ws, size_t ws_size,
                              hipStream_t stream) {
  const float* dist = (const float*)d_in[0];
  const float* azim = (const float*)d_in[1];
  const float* elev = (const float*)d_in[2];
  // d_in[3] spike_count: unused by the reference
  const float* Wd = (const float*)d_in[4];
  const float* bd = (const float*)d_in[5];
  const float* Wa = (const float*)d_in[6];
  const float* ba = (const float*)d_in[7];
  const float* We = (const float*)d_in[8];
  const float* be = (const float*)d_in[9];
  const float* Wf = (const float*)d_in[10];
  const float* bf = (const float*)d_in[11];
  const float* Wi = (const float*)d_in[12];
  const float* bi = (const float*)d_in[13];
  const float* Wo = (const float*)d_in[14];
  const float* bo = (const float*)d_in[15];

  char* ws = (char*)d_ws;
  const size_t MB = 1u << 20;
  // Footprint 136 MB, no aliasing.
  float* FUSED = (float*)(ws);             // [0,48)   4096x3072 f32
  float* FC    = (float*)(ws + 48 * MB);   // [48,80)  4096x2048 f32
  u16*   SPK   = (u16*)(ws + 80 * MB);     // [80,96)  4096x2048 u16 bitmask
  float* IMEM  = (float*)(ws + 96 * MB);   // [96,128) 4096x2048 f32
  u8*    CNT   = (u8*)(ws + 128 * MB);     // [128,136) 4096x2048 u8

  lat_kernel<<<dim3(48, 64), 256, 0, stream>>>(dist, azim, elev, Wd, bd, Wa, ba, We, be, FUSED);
  fusion_kernel<<<dim3(16, 32), 256, 0, stream>>>(FUSED, Wf, bf, FC);
  spikegen16_kernel<<<(B_ * H_) / 256, 256, 0, stream>>>(FC, SPK);
  for (int t = 0; t < T_; ++t)
    isgemm_kernel<<<dim3(32, 16), 256, 0, stream>>>(SPK, Wi, bi, IMEM, CNT, t);
  out_kernel<<<(B_ * O_) / 256, 256, 0, stream>>>(CNT, Wo, bo, (float*)d_out);
}